// Round 10
// baseline (206.110 us; speedup 1.0000x reference)
//
#include <hip/hip_runtime.h>

#define BSZ   2
#define TSEQ  2048
#define DMOD  1024
#define NHEAD 16
#define HDIM  64
#define MROW  (BSZ*TSEQ)
#define LNEPS 1e-5f
#define QSCALE 0.18033688011f   // (1/8)*log2(e): softmax in exp2 domain

typedef __bf16 bf16x8 __attribute__((ext_vector_type(8)));
typedef float  f32x4  __attribute__((ext_vector_type(4)));
typedef unsigned short us8 __attribute__((ext_vector_type(8)));
typedef unsigned short us4 __attribute__((ext_vector_type(4)));

__device__ __forceinline__ unsigned short f2bf(float f) {
    unsigned u = __float_as_uint(f);
    u += 0x7FFF + ((u >> 16) & 1);        // RNE
    return (unsigned short)(u >> 16);
}
__device__ __forceinline__ float bf2f(unsigned short u) {
    return __uint_as_float((unsigned)u << 16);
}

__device__ __forceinline__ float fexp2(float x) {
#if __has_builtin(__builtin_amdgcn_exp2f)
    return __builtin_amdgcn_exp2f(x);     // raw v_exp_f32
#else
    return __expf(x * 0.6931471805599453f);
#endif
}

__device__ __forceinline__ void gld_lds16(const void* g, void* l) {
    __builtin_amdgcn_global_load_lds(
        (const __attribute__((address_space(1))) unsigned int*)g,
        (__attribute__((address_space(3))) unsigned int*)l, 16, 0, 0);
}

// ---------------- fused prep: x->bf16 (blocks 0..2047) + 4x W^T (2048..3071)
__global__ __launch_bounds__(256) void prep_k(
    const float* __restrict__ x,
    const float* __restrict__ wq, const float* __restrict__ wk,
    const float* __restrict__ wv, const float* __restrict__ wo,
    unsigned short* __restrict__ Xb,
    unsigned short* __restrict__ WqkvT, unsigned short* __restrict__ WoT)
{
    const int tid = threadIdx.x;
    if (blockIdx.x < 2048) {
        const size_t i = ((size_t)blockIdx.x * 256 + tid) * 8;
        float4 a = *(const float4*)&x[i];
        float4 b = *(const float4*)&x[i + 4];
        union { unsigned short u[8]; uint4 v; } o;
        o.u[0]=f2bf(a.x); o.u[1]=f2bf(a.y); o.u[2]=f2bf(a.z); o.u[3]=f2bf(a.w);
        o.u[4]=f2bf(b.x); o.u[5]=f2bf(b.y); o.u[6]=f2bf(b.z); o.u[7]=f2bf(b.w);
        *(uint4*)&Xb[i] = o.v;
        return;
    }
    __shared__ float T[64][68];
    const int id = blockIdx.x - 2048;
    const int z  = id >> 8;
    const int bx = id & 15;
    const int by = (id >> 4) & 15;
    const float* W = (z == 0) ? wq : (z == 1) ? wk : (z == 2) ? wv : wo;
    unsigned short* Wt = (z < 3) ? (WqkvT + (size_t)z*1024*1024) : WoT;
    const int lr = tid >> 4, lc = (tid & 15) * 4;
    #pragma unroll
    for (int p = 0; p < 4; ++p) {
        const int kk = p*16 + lr;
        float4 v = *(const float4*)&W[(size_t)(by*64 + kk)*1024 + bx*64 + lc];
        T[lc+0][kk] = v.x; T[lc+1][kk] = v.y; T[lc+2][kk] = v.z; T[lc+3][kk] = v.w;
    }
    __syncthreads();
    #pragma unroll
    for (int p = 0; p < 2; ++p) {
        const int nl = p*32 + (tid >> 3);
        const int kb = (tid & 7) * 8;
        float4 a = *(const float4*)&T[nl][kb];
        float4 b = *(const float4*)&T[nl][kb+4];
        union { unsigned short u[8]; uint4 v; } o;
        o.u[0]=f2bf(a.x); o.u[1]=f2bf(a.y); o.u[2]=f2bf(a.z); o.u[3]=f2bf(a.w);
        o.u[4]=f2bf(b.x); o.u[5]=f2bf(b.y); o.u[6]=f2bf(b.z); o.u[7]=f2bf(b.w);
        *(uint4*)&Wt[(size_t)(bx*64 + nl)*1024 + by*64 + kb] = o.v;
    }
}

// ======== ping-pong BK=32 MFMA GEMM core (128x128 tile, 4 waves) ===========
// LDS: 4 buffers of 128x32 bf16 (8 KB): A0,A1,B0,B1 = 32 KB total.
// Row layout: 32 elems (64 B) = 4 chunks of 16 B; chunk slot p of row R holds
// global chunk p ^ (R&3) -> frag ds_read_b128 lands <=2-way (free), staging
// stays wave-uniform-base contiguous for global_load_lds.
// K-loop: ONE __syncthreads per BK=32 tile, ordered
//   barrier (drains loads issued last iter - they overlapped compute)
//   -> issue loads tile i+1 -> compute tile i.
// SWAP=1: mfma(w,x) -> C rows=n, cols=m (epilogue packs us4 along n).
struct GemmFrags {
    const unsigned short* Ag[2]; const unsigned short* Bg[2];
    int ldso[2];        // staging LDS offset (elems) within a buffer
    int apo[4], bpo[4]; // frag offsets (elems) within a buffer
};

__device__ __forceinline__ void gemm_setup(
    GemmFrags& F, const unsigned short* A, const unsigned short* Bt,
    int bm, int bn, int lda)
{
    const int tid  = threadIdx.x;
    const int wv   = tid >> 6;
    const int lane = tid & 63;
    const int quad = lane >> 4;
    const int l16  = lane & 15;
    const int wm   = wv & 1, wn = wv >> 1;
    const int r_l = lane >> 2;     // 0..15 row within round
    const int c_l = lane & 3;      // chunk slot
    #pragma unroll
    for (int s = 0; s < 2; ++s) {
        const int R = wv*32 + s*16 + r_l;
        const int gc = (c_l ^ (r_l & 3)) * 8;    // R&3 == r_l&3
        F.Ag[s] = A  + (size_t)(bm + R)*lda + gc;
        F.Bg[s] = Bt + (size_t)(bn + R)*lda + gc;
        F.ldso[s] = (wv*32 + s*16)*32;           // wave-uniform
    }
    #pragma unroll
    for (int t = 0; t < 4; ++t) {
        const int ra = wm*64 + t*16 + l16;
        const int rb = wn*64 + t*16 + l16;
        F.apo[t] = ra*32 + ((quad ^ (ra & 3))*8);
        F.bpo[t] = rb*32 + ((quad ^ (rb & 3))*8);
    }
}

__device__ __forceinline__ void gemm_load(
    GemmFrags& F, unsigned short* SA, unsigned short* SB, int k0)
{
    #pragma unroll
    for (int s = 0; s < 2; ++s) {
        gld_lds16(F.Ag[s] + k0, SA + F.ldso[s]);
        gld_lds16(F.Bg[s] + k0, SB + F.ldso[s]);
    }
}

template<int SWAP>
__device__ __forceinline__ void gemm_compute(
    GemmFrags& F, const unsigned short* SA, const unsigned short* SB,
    f32x4 (&acc)[4][4])
{
    bf16x8 af[4], bfr[4];
    #pragma unroll
    for (int t = 0; t < 4; ++t) {
        af[t]  = *(const bf16x8*)(SA + F.apo[t]);
        bfr[t] = *(const bf16x8*)(SB + F.bpo[t]);
    }
    #pragma unroll
    for (int i = 0; i < 4; ++i)
        #pragma unroll
        for (int j = 0; j < 4; ++j)
            acc[i][j] = SWAP
                ? __builtin_amdgcn_mfma_f32_16x16x32_bf16(bfr[j], af[i], acc[i][j], 0, 0, 0)
                : __builtin_amdgcn_mfma_f32_16x16x32_bf16(af[i], bfr[j], acc[i][j], 0, 0, 0);
}

// S layout (elems): A0=0, A1=4096, B0=8192, B1=12288
template<int SWAP>
__device__ __forceinline__ void gemm_kloop(
    GemmFrags& F, unsigned short* S, f32x4 (&acc)[4][4], int kb, int ke)
{
    unsigned short* A0 = S;         unsigned short* A1 = S + 4096;
    unsigned short* B0 = S + 8192;  unsigned short* B1 = S + 12288;
    gemm_load(F, A0, B0, kb);
    for (int k0 = kb; k0 < ke; k0 += 64) {
        __syncthreads();                       // cheap drain: buf0 loads overlapped
        gemm_load(F, A1, B1, k0 + 32);         // k0+32 < ke always (step 64)
        gemm_compute<SWAP>(F, A0, B0, acc);
        __syncthreads();
        if (k0 + 64 < ke) gemm_load(F, A0, B0, k0 + 64);
        gemm_compute<SWAP>(F, A1, B1, acc);
    }
}

// ---------------- QKV GEMM: N=3072, BK=32 pp. seg 0->Q(scaled) 1->K 2->V^T --
__global__ __launch_bounds__(256) void gemm_qkv_k(
    const unsigned short* __restrict__ A, const unsigned short* __restrict__ Bt,
    const float* __restrict__ b0, const float* __restrict__ b1,
    const float* __restrict__ b2,
    unsigned short* __restrict__ oQ, unsigned short* __restrict__ oK,
    unsigned short* __restrict__ oV)
{
    __shared__ unsigned short S[4*4096];
    const int tid  = threadIdx.x;
    const int wv   = tid >> 6;
    const int lane = tid & 63;
    const int quad = lane >> 4;
    const int l16  = lane & 15;
    const int wm   = wv & 1, wn = wv >> 1;
    const int bm = blockIdx.y * 128, bn = blockIdx.x * 128;

    GemmFrags F;
    gemm_setup(F, A, Bt, bm, bn, 1024);

    f32x4 acc[4][4];
    #pragma unroll
    for (int i = 0; i < 4; ++i)
        #pragma unroll
        for (int j = 0; j < 4; ++j) acc[i][j] = (f32x4){0.f,0.f,0.f,0.f};

    const int seg = bn >> 10;                 // uniform per block
    const float* bias = (seg == 0) ? b0 : (seg == 1) ? b1 : b2;
    const int cb = bn & 1023;

    if (seg < 2) {
        // swapped: C rows = n (quad*4+r), cols = m (l16) -> us4 stores along n
        gemm_kloop<1>(F, S, acc, 0, 1024);
        unsigned short* O = (seg == 0) ? oQ : oK;
        const float sc = (seg == 0) ? QSCALE : 1.0f;
        #pragma unroll
        for (int mt = 0; mt < 4; ++mt) {
            const int m = bm + wm*64 + mt*16 + l16;
            #pragma unroll
            for (int nt = 0; nt < 4; ++nt) {
                const int n0 = cb + wn*64 + nt*16 + quad*4;
                const f32x4 bs = *(const f32x4*)&bias[n0];
                us4 o;
                #pragma unroll
                for (int r = 0; r < 4; ++r) o[r] = f2bf((acc[mt][nt][r] + bs[r]) * sc);
                *(us4*)&O[(size_t)m*1024 + n0] = o;
            }
        }
    } else {
        // normal: C rows = m (quad*4+r) -> us4 stores along tokens in V^T
        gemm_kloop<0>(F, S, acc, 0, 1024);
        #pragma unroll
        for (int nt = 0; nt < 4; ++nt) {
            const int ch = cb + wn*64 + nt*16 + l16;
            const float bs = bias[ch];
            #pragma unroll
            for (int mt = 0; mt < 4; ++mt) {
                const int grow0 = bm + wm*64 + mt*16 + quad*4;
                us4 o;
                #pragma unroll
                for (int r = 0; r < 4; ++r) o[r] = f2bf(acc[mt][nt][r] + bs);
                *(us4*)&oV[(size_t)ch*MROW + grow0] = o;
            }
        }
    }
}

// ---------------- proj GEMM split-K=2: partial bf16, no bias ---------------
__global__ __launch_bounds__(256) void gemm_proj_k(
    const unsigned short* __restrict__ A, const unsigned short* __restrict__ Bt,
    unsigned short* __restrict__ P)   // [2][MROW][1024]
{
    __shared__ unsigned short S[4*4096];
    const int tid  = threadIdx.x;
    const int wv   = tid >> 6;
    const int lane = tid & 63;
    const int quad = lane >> 4;
    const int l16  = lane & 15;
    const int wm   = wv & 1, wn = wv >> 1;
    const int bm = blockIdx.y * 128, bn = blockIdx.x * 128;
    const int kz = blockIdx.z;

    GemmFrags F;
    gemm_setup(F, A, Bt, bm, bn, 1024);

    f32x4 acc[4][4];
    #pragma unroll
    for (int i = 0; i < 4; ++i)
        #pragma unroll
        for (int j = 0; j < 4; ++j) acc[i][j] = (f32x4){0.f,0.f,0.f,0.f};

    gemm_kloop<1>(F, S, acc, kz*512, kz*512 + 512);

    unsigned short* O = P + (size_t)kz*MROW*1024;
    #pragma unroll
    for (int mt = 0; mt < 4; ++mt) {
        const int m = bm + wm*64 + mt*16 + l16;
        #pragma unroll
        for (int nt = 0; nt < 4; ++nt) {
            const int n0 = bn + wn*64 + nt*16 + quad*4;
            us4 o;
            #pragma unroll
            for (int r = 0; r < 4; ++r) o[r] = f2bf(acc[mt][nt][r]);
            *(us4*)&O[(size_t)m*1024 + n0] = o;
        }
    }
}

// ---------------- flash attention v3 (unchanged) ---------------------------
__global__ __launch_bounds__(256, 2) void attn_k(
    const unsigned short* __restrict__ Qg,
    const unsigned short* __restrict__ Kg,
    const unsigned short* __restrict__ Vtg,
    unsigned short* __restrict__ CTX)
{
    __shared__ __align__(16) char lds_raw[51200];
    unsigned short* Qs = (unsigned short*)lds_raw;            // [128][72]
    unsigned short* Ks = (unsigned short*)(lds_raw + 18432);  // [2][64][64]
    unsigned short* Vs = (unsigned short*)(lds_raw + 34816);  // [2][64][64]
    float* Od = (float*)lds_raw;                              // [2][64][68]
    float* Ld = (float*)(lds_raw + 34816);                    // [2][64]

    const int tid  = threadIdx.x;
    const int wv   = tid >> 6;
    const int lane = tid & 63;
    const int quad = lane >> 4;
    const int l16  = lane & 15;
    const int wq   = wv & 1;
    const int wk   = wv >> 1;
    const int qb   = blockIdx.x * 128;
    const int h    = blockIdx.y;
    const int b    = blockIdx.z;

    {
        const int row = tid & 127, cb = (tid >> 7) * 32;
        const unsigned short* Qrow = Qg + ((size_t)(b*TSEQ + qb + row))*DMOD + h*HDIM + cb;
        #pragma unroll
        for (int j = 0; j < 4; ++j)
            *(us8*)&Qs[row*72 + cb + j*8] = *(const us8*)&Qrow[j*8];
    }
    __syncthreads();
    bf16x8 qf[4][2];
    #pragma unroll
    for (int nt = 0; nt < 4; ++nt)
        #pragma unroll
        for (int kh = 0; kh < 2; ++kh)
            qf[nt][kh] = *(const bf16x8*)&Qs[(wq*64 + nt*16 + l16)*72 + kh*32 + quad*8];

    const int sr = lane >> 3;
    const int sc = lane & 7;
    const bool isK = (wv < 2);
    const int half = wv & 1;
    const unsigned short* gbase;
    unsigned int goff[8];
    unsigned short* ldst;
    if (isK) {
        gbase = Kg + ((size_t)(b*TSEQ + half*1024))*DMOD + h*HDIM;
        #pragma unroll
        for (int s = 0; s < 8; ++s) {
            const int R = s*8 + sr;
            const int gc = sc ^ ((R ^ (R >> 2)) & 7);
            goff[s] = (unsigned)(R*DMOD + gc*8);
        }
        ldst = Ks + half*4096;
    } else {
        gbase = Vtg + ((size_t)(h*HDIM))*MROW + b*TSEQ + half*1024;
        #pragma unroll
        for (int s = 0; s < 8; ++s) {
            const int D = s*8 + sr;
            const int gc = sc ^ (D & 7);
            goff[s] = (unsigned)(D*MROW + gc*8);
        }
        ldst = Vs + half*4096;
    }
    const size_t gstep = isK ? (size_t)64*DMOD : (size_t)64;

    const int rowA_l = (l16 >> 2)*8 + (l16 & 3);
    const int rowB_l = rowA_l + 4;
    const int swA = (rowA_l ^ (rowA_l >> 2)) & 7;
    const int swB = (rowB_l ^ (rowB_l >> 2)) & 7;
    const unsigned short* KsW = Ks + wk*4096;
    const unsigned short* VsW = Vs + wk*4096;

    bf16x8 onef;
    { union { unsigned short u[8]; bf16x8 v; } o1;
      #pragma unroll
      for (int i = 0; i < 8; ++i) o1.u[i] = 0x3F80;
      onef = o1.v; }

    f32x4 oacc[4][4];
    f32x4 lacc[4];
    #pragma unroll
    for (int dt = 0; dt < 4; ++dt)
        #pragma unroll
        for (int nt = 0; nt < 4; ++nt) oacc[dt][nt] = (f32x4){0.f,0.f,0.f,0.f};
    #pragma unroll
    for (int nt = 0; nt < 4; ++nt) lacc[nt] = (f32x4){0.f,0.f,0.f,0.f};

    for (int it = 0; it < 16; ++it) {
        __syncthreads();
        #pragma unroll
        for (int s = 0; s < 8; ++s)
            gld_lds16(gbase + (size_t)it*gstep + goff[s], ldst + s*512);
        __syncthreads();

        #pragma unroll
        for (int gl = 0; gl < 2; ++gl) {
            const int rA = gl*32 + rowA_l;
            const int rB = gl*32 + rowB_l;
            bf16x8 ka0 = *(const bf16x8*)&KsW[rA*64 + ((quad     ^ swA))*8];
            bf16x8 ka1 = *(const bf16x8*)&KsW[rA*64 + (((4+quad) ^ swA))*8];
            bf16x8 kb0 = *(const bf16x8*)&KsW[rB*64 + ((quad     ^ swB))*8];
            bf16x8 kb1 = *(const bf16x8*)&KsW[rB*64 + (((4+quad) ^ swB))*8];
            bf16x8 vf[4];
            #pragma unroll
            for (int dt = 0; dt < 4; ++dt)
                vf[dt] = *(const bf16x8*)&VsW[(dt*16 + l16)*64 + ((gl*4 + quad) ^ (l16 & 7))*8];

            #pragma unroll
            for (int nt = 0; nt < 4; ++nt) {
                f32x4 z = (f32x4){0.f,0.f,0.f,0.f};
                z = __builtin_amdgcn_mfma_f32_16x16x32_bf16(ka0, qf[nt][0], z, 0, 0, 0);
                f32x4 sA = __builtin_amdgcn_mfma_f32_16x16x32_bf16(ka1, qf[nt][1], z, 0, 0, 0);
                z = (f32x4){0.f,0.f,0.f,0.f};
                z = __builtin_amdgcn_mfma_f32_16x16x32_bf16(kb0, qf[nt][0], z, 0, 0, 0);
                f32x4 sB = __builtin_amdgcn_mfma_f32_16x16x32_bf16(kb1, qf[nt][1], z, 0, 0, 0);

                float eA[4], eB[4];
                #pragma unroll
                for (int r = 0; r < 4; ++r) { eA[r] = fexp2(sA[r]); eB[r] = fexp2(sB[r]); }
                union { unsigned d[4]; bf16x8 v; } up;
                up.d[0] = __builtin_amdgcn_perm(__float_as_uint(eA[1]), __float_as_uint(eA[0]), 0x07060302);
                up.d[1] = __builtin_amdgcn_perm(__float_as_uint(eA[3]), __float_as_uint(eA[2]), 0x07060302);
                up.d[2] = __builtin_amdgcn_perm(__float_as_uint(eB[1]), __float_as_uint(eB[0]), 0x07060302);
                up.d[3] = __builtin_amdgcn_perm(__float_as_uint(eB[3]), __float_as_uint(eB[2]), 0x07060302);
                const bf16x8 pf = up.v;

                lacc[nt] = __builtin_amdgcn_mfma_f32_16x16x32_bf16(onef, pf, lacc[nt], 0, 0, 0);
                #pragma unroll
                for (int dt = 0; dt < 4; ++dt)
                    oacc[dt][nt] = __builtin_amdgcn_mfma_f32_16x16x32_bf16(vf[dt], pf, oacc[dt][nt], 0, 0, 0);
            }
        }
    }

    __syncthreads();
    if (wk == 0) {
        float* od = Od + wq*64*68;
        #pragma unroll
        for (int nt = 0; nt < 4; ++nt) {
            #pragma unroll
            for (int dt = 0; dt < 4; ++dt)
                *(f32x4*)&od[(nt*16 + l16)*68 + dt*16 + quad*4] = oacc[dt][nt];
            if (quad == 0) Ld[wq*64 + nt*16 + l16] = lacc[nt][0];
        }
    }
    __syncthreads();
    if (wk == 1) {
        const float* od = Od + wq*64*68;
        #pragma unroll
        for (int nt = 0; nt < 4; ++nt) {
            const float l = Ld[wq*64 + nt*16 + l16] + lacc[nt][0];
            const float inv = 1.f / l;
            const int q = qb + wq*64 + nt*16 + l16;
            unsigned short* crow = CTX + ((size_t)(b*TSEQ + q))*DMOD + h*HDIM;
            #pragma unroll
            for (int dt = 0; dt < 4; ++dt) {
                f32x4 p = *(const f32x4*)&od[(nt*16 + l16)*68 + dt*16 + quad*4];
                us4 o;
                #pragma unroll
                for (int r = 0; r < 4; ++r) o[r] = f2bf((p[r] + oacc[dt][nt][r]) * inv);
                *(us4*)&crow[dt*16 + quad*4] = o;
            }
        }
    }
}

// ---------- split-K reduce + bias + residual + LayerNorm -------------------
__global__ __launch_bounds__(256) void red_ln_k(
    const float* __restrict__ x, const unsigned short* __restrict__ P,
    const float* __restrict__ bo,
    const float* __restrict__ gamma, const float* __restrict__ beta,
    float* __restrict__ out)
{
    __shared__ float rs[4], rss[4];
    const int row = blockIdx.x;
    const int tid = threadIdx.x;
    const int c = tid * 4;
    const float4 xv = *(const float4*)&x[(size_t)row*DMOD + c];
    const us4 p0 = *(const us4*)&P[(size_t)row*DMOD + c];
    const us4 p1 = *(const us4*)&P[(size_t)(MROW + row)*DMOD + c];
    const float4 bv4 = *(const float4*)&bo[c];
    const float v0 = xv.x + bf2f(p0[0]) + bf2f(p1[0]) + bv4.x;
    const float v1 = xv.y + bf2f(p0[1]) + bf2f(p1[1]) + bv4.y;
    const float v2 = xv.z + bf2f(p0[2]) + bf2f(p1[2]) + bv4.z;
    const float v3 = xv.w + bf2f(p0[3]) + bf2f(p1[3]) + bv4.w;
    float s  = v0 + v1 + v2 + v3;
    float ss = v0*v0 + v1*v1 + v2*v2 + v3*v3;
    #pragma unroll
    for (int o = 32; o > 0; o >>= 1) {
        s  += __shfl_down(s,  o, 64);
        ss += __shfl_down(ss, o, 64);
    }
    if ((tid & 63) == 0) { rs[tid >> 6] = s; rss[tid >> 6] = ss; }
    __syncthreads();
    s  = rs[0] + rs[1] + rs[2] + rs[3];
    ss = rss[0] + rss[1] + rss[2] + rss[3];
    const float mean = s * (1.f/DMOD);
    const float var  = ss * (1.f/DMOD) - mean*mean;
    const float rstd = rsqrtf(var + LNEPS);
    const float4 gv = *(const float4*)&gamma[c];
    const float4 bv = *(const float4*)&beta[c];
    float4 o;
    o.x = (v0 - mean)*rstd*gv.x + bv.x;
    o.y = (v1 - mean)*rstd*gv.y + bv.y;
    o.z = (v2 - mean)*rstd*gv.z + bv.z;
    o.w = (v3 - mean)*rstd*gv.w + bv.w;
    *(float4*)&out[(size_t)row*DMOD + c] = o;
}

extern "C" void kernel_launch(void* const* d_in, const int* in_sizes, int n_in,
                              void* d_out, int out_size, void* d_ws, size_t ws_size,
                              hipStream_t stream) {
    const float* x     = (const float*)d_in[0];
    const float* wq    = (const float*)d_in[1];
    const float* bq    = (const float*)d_in[2];
    const float* wk    = (const float*)d_in[3];
    const float* bk    = (const float*)d_in[4];
    const float* wvp   = (const float*)d_in[5];
    const float* bvp   = (const float*)d_in[6];
    const float* wo    = (const float*)d_in[7];
    const float* bo    = (const float*)d_in[8];
    const float* gamma = (const float*)d_in[9];
    const float* beta  = (const float*)d_in[10];
    float* out = (float*)d_out;

    // ws layout (bf16 elems), 48 MB total
    unsigned short* Xb    = (unsigned short*)d_ws;          // [4096][1024]
    unsigned short* WqkvT = Xb    + (size_t)MROW*DMOD;      // [3072][1024]
    unsigned short* WoT   = WqkvT + (size_t)3072*1024;      // [1024][1024]
    unsigned short* Qb    = WoT   + (size_t)1024*1024;      // [4096][1024]
    unsigned short* Kb    = Qb    + (size_t)MROW*DMOD;      // [4096][1024]
    unsigned short* VtG   = Kb    + (size_t)MROW*DMOD;      // [1024][4096]
    unsigned short* CTXb  = VtG   + (size_t)DMOD*MROW;      // [4096][1024]
    unsigned short* Pp    = Qb;   // proj partials [2][4096][1024] overlay Qb+Kb

    prep_k<<<3072, 256, 0, stream>>>(x, wq, wk, wvp, wo, Xb, WqkvT, WoT);

    gemm_qkv_k<<<dim3(3072/128, MROW/128), 256, 0, stream>>>(
        Xb, WqkvT, bq, bk, bvp, Qb, Kb, VtG);

    attn_k<<<dim3(TSEQ/128, NHEAD, BSZ), 256, 0, stream>>>(Qb, Kb, VtG, CTXb);

    gemm_proj_k<<<dim3(DMOD/128, MROW/128, 2), 256, 0, stream>>>(CTXb, WoT, Pp);

    red_ln_k<<<MROW, 256, 0, stream>>>(x, Pp, bo, gamma, beta, out);
}

// Round 11
// 196.895 us; speedup vs baseline: 1.0468x; 1.0468x over previous
//
#include <hip/hip_runtime.h>

#define BSZ   2
#define TSEQ  2048
#define DMOD  1024
#define NHEAD 16
#define HDIM  64
#define MROW  (BSZ*TSEQ)
#define LNEPS 1e-5f
#define QSCALE 0.18033688011f   // (1/8)*log2(e): softmax in exp2 domain

typedef __bf16 bf16x8 __attribute__((ext_vector_type(8)));
typedef float  f32x4  __attribute__((ext_vector_type(4)));
typedef unsigned short us8 __attribute__((ext_vector_type(8)));
typedef unsigned short us4 __attribute__((ext_vector_type(4)));

__device__ __forceinline__ unsigned short f2bf(float f) {
    unsigned u = __float_as_uint(f);
    u += 0x7FFF + ((u >> 16) & 1);        // RNE
    return (unsigned short)(u >> 16);
}
__device__ __forceinline__ float bf2f(unsigned short u) {
    return __uint_as_float((unsigned)u << 16);
}

__device__ __forceinline__ float fexp2(float x) {
#if __has_builtin(__builtin_amdgcn_exp2f)
    return __builtin_amdgcn_exp2f(x);     // raw v_exp_f32
#else
    return __expf(x * 0.6931471805599453f);
#endif
}

__device__ __forceinline__ void gld_lds16(const void* g, void* l) {
    __builtin_amdgcn_global_load_lds(
        (const __attribute__((address_space(1))) unsigned int*)g,
        (__attribute__((address_space(3))) unsigned int*)l, 16, 0, 0);
}

// ---------------- fused prep: x->bf16 (blocks 0..2047) + 4x W^T (2048..3071)
// W^T via in-register 4x4 transpose: no LDS -> no bank conflicts.
__global__ __launch_bounds__(256) void prep_k(
    const float* __restrict__ x,
    const float* __restrict__ wq, const float* __restrict__ wk,
    const float* __restrict__ wv, const float* __restrict__ wo,
    unsigned short* __restrict__ Xb,
    unsigned short* __restrict__ WqkvT, unsigned short* __restrict__ WoT)
{
    const int tid = threadIdx.x;
    if (blockIdx.x < 2048) {
        const size_t i = ((size_t)blockIdx.x * 256 + tid) * 8;
        float4 a = *(const float4*)&x[i];
        float4 b = *(const float4*)&x[i + 4];
        union { unsigned short u[8]; uint4 v; } o;
        o.u[0]=f2bf(a.x); o.u[1]=f2bf(a.y); o.u[2]=f2bf(a.z); o.u[3]=f2bf(a.w);
        o.u[4]=f2bf(b.x); o.u[5]=f2bf(b.y); o.u[6]=f2bf(b.z); o.u[7]=f2bf(b.w);
        *(uint4*)&Xb[i] = o.v;
        return;
    }
    const int id = blockIdx.x - 2048;
    const int z  = id >> 8;
    const int bx = id & 15;            // n-tile
    const int by = (id >> 4) & 15;     // k-tile
    const float* W = (z == 0) ? wq : (z == 1) ? wk : (z == 2) ? wv : wo;
    unsigned short* Wt = (z < 3) ? (WqkvT + (size_t)z*1024*1024) : WoT;
    const int n0 = (tid & 15) * 4;
    const int k0 = (tid >> 4) * 4;
    const float* Wp = W + (size_t)(by*64 + k0)*1024 + bx*64 + n0;
    const float4 r0 = *(const float4*)(Wp);
    const float4 r1 = *(const float4*)(Wp + 1024);
    const float4 r2 = *(const float4*)(Wp + 2048);
    const float4 r3 = *(const float4*)(Wp + 3072);
    unsigned short* Wo = Wt + (size_t)(bx*64 + n0)*1024 + by*64 + k0;
    *(us4*)(Wo)        = (us4){f2bf(r0.x), f2bf(r1.x), f2bf(r2.x), f2bf(r3.x)};
    *(us4*)(Wo + 1024) = (us4){f2bf(r0.y), f2bf(r1.y), f2bf(r2.y), f2bf(r3.y)};
    *(us4*)(Wo + 2048) = (us4){f2bf(r0.z), f2bf(r1.z), f2bf(r2.z), f2bf(r3.z)};
    *(us4*)(Wo + 3072) = (us4){f2bf(r0.w), f2bf(r1.w), f2bf(r2.w), f2bf(r3.w)};
}

// ======== BK=64 MFMA GEMM core (128x128 tile, both operands in LDS) ========
// (r9 core: 0 bank conflicts, 43.4 us QKV — reverted from r10 ping-pong.)
// LDS layout: [128 rows][64 elems], chunk p of row R holds global chunk
// p ^ (R&7) -> frag b128 reads conflict-free, staging coalesced.
// SWAP=1: mfma(w_frag, x_frag) -> C rows = n, cols = m  (epilogue packs us4
// along n for row-major outputs). SWAP=0: normal (V^T epilogue packs tokens).
struct GemmFrags {
    const unsigned short* Ag[4]; const unsigned short* Bg[4];
    unsigned short *la[4], *lb[4];
    const unsigned short *ap[4][2], *bp[4][2];
};

__device__ __forceinline__ void gemm_setup(
    GemmFrags& F, unsigned short* As, unsigned short* Bs,
    const unsigned short* A, const unsigned short* Bt,
    int bm, int bn, int lda)
{
    const int tid  = threadIdx.x;
    const int wv   = tid >> 6;
    const int lane = tid & 63;
    const int quad = lane >> 4;
    const int l16  = lane & 15;
    const int wm   = wv & 1, wn = wv >> 1;
    const int r_l = lane >> 3;
    const int c_l = lane & 7;
    #pragma unroll
    for (int s = 0; s < 4; ++s) {
        const int i = wv*4 + s;
        const int R = i*8 + r_l;
        const int gc = (c_l ^ (R & 7)) * 8;
        F.Ag[s] = A  + (size_t)(bm + R)*lda + gc;
        F.Bg[s] = Bt + (size_t)(bn + R)*lda + gc;
        F.la[s] = As + i*512;
        F.lb[s] = Bs + i*512;
    }
    #pragma unroll
    for (int t = 0; t < 4; ++t)
        #pragma unroll
        for (int kh = 0; kh < 2; ++kh) {
            const int ra = wm*64 + t*16 + l16;
            const int rb = wn*64 + t*16 + l16;
            F.ap[t][kh] = &As[ra*64 + ((kh*4 + quad) ^ (ra & 7))*8];
            F.bp[t][kh] = &Bs[rb*64 + ((kh*4 + quad) ^ (rb & 7))*8];
        }
}

template<int SWAP>
__device__ __forceinline__ void gemm_kloop(
    GemmFrags& F, f32x4 (&acc)[4][4], int k_begin, int k_end)
{
    for (int k0 = k_begin; k0 < k_end; k0 += 64) {
        __syncthreads();
        #pragma unroll
        for (int s = 0; s < 4; ++s) {
            gld_lds16(F.Ag[s] + k0, F.la[s]);
            gld_lds16(F.Bg[s] + k0, F.lb[s]);
        }
        __syncthreads();
        #pragma unroll
        for (int kh = 0; kh < 2; ++kh) {
            bf16x8 af[4], bfr[4];
            #pragma unroll
            for (int t = 0; t < 4; ++t) {
                af[t]  = *(const bf16x8*)F.ap[t][kh];
                bfr[t] = *(const bf16x8*)F.bp[t][kh];
            }
            #pragma unroll
            for (int i = 0; i < 4; ++i)
                #pragma unroll
                for (int j = 0; j < 4; ++j)
                    acc[i][j] = SWAP
                        ? __builtin_amdgcn_mfma_f32_16x16x32_bf16(bfr[j], af[i], acc[i][j], 0, 0, 0)
                        : __builtin_amdgcn_mfma_f32_16x16x32_bf16(af[i], bfr[j], acc[i][j], 0, 0, 0);
        }
    }
}

// ---------------- QKV GEMM: N=3072, BK=64. seg 0->Q(scaled) 1->K 2->V^T ----
__global__ __launch_bounds__(256) void gemm_qkv_k(
    const unsigned short* __restrict__ A, const unsigned short* __restrict__ Bt,
    const float* __restrict__ b0, const float* __restrict__ b1,
    const float* __restrict__ b2,
    unsigned short* __restrict__ oQ, unsigned short* __restrict__ oK,
    unsigned short* __restrict__ oV)
{
    __shared__ unsigned short As[128*64];
    __shared__ unsigned short Bs[128*64];
    const int tid  = threadIdx.x;
    const int wv   = tid >> 6;
    const int lane = tid & 63;
    const int quad = lane >> 4;
    const int l16  = lane & 15;
    const int wm   = wv & 1, wn = wv >> 1;
    const int bm = blockIdx.y * 128, bn = blockIdx.x * 128;

    GemmFrags F;
    gemm_setup(F, As, Bs, A, Bt, bm, bn, 1024);

    f32x4 acc[4][4];
    #pragma unroll
    for (int i = 0; i < 4; ++i)
        #pragma unroll
        for (int j = 0; j < 4; ++j) acc[i][j] = (f32x4){0.f,0.f,0.f,0.f};

    const int seg = bn >> 10;                 // uniform per block
    const float* bias = (seg == 0) ? b0 : (seg == 1) ? b1 : b2;
    const int cb = bn & 1023;

    if (seg < 2) {
        // swapped: C rows = n (quad*4+r), cols = m (l16) -> us4 stores along n
        gemm_kloop<1>(F, acc, 0, 1024);
        unsigned short* O = (seg == 0) ? oQ : oK;
        const float sc = (seg == 0) ? QSCALE : 1.0f;
        #pragma unroll
        for (int mt = 0; mt < 4; ++mt) {
            const int m = bm + wm*64 + mt*16 + l16;
            #pragma unroll
            for (int nt = 0; nt < 4; ++nt) {
                const int n0 = cb + wn*64 + nt*16 + quad*4;
                const f32x4 bs = *(const f32x4*)&bias[n0];
                us4 o;
                #pragma unroll
                for (int r = 0; r < 4; ++r) o[r] = f2bf((acc[mt][nt][r] + bs[r]) * sc);
                *(us4*)&O[(size_t)m*1024 + n0] = o;
            }
        }
    } else {
        // normal: C rows = m (quad*4+r) -> us4 stores along tokens in V^T
        gemm_kloop<0>(F, acc, 0, 1024);
        #pragma unroll
        for (int nt = 0; nt < 4; ++nt) {
            const int ch = cb + wn*64 + nt*16 + l16;
            const float bs = bias[ch];
            #pragma unroll
            for (int mt = 0; mt < 4; ++mt) {
                const int grow0 = bm + wm*64 + mt*16 + quad*4;
                us4 o;
                #pragma unroll
                for (int r = 0; r < 4; ++r) o[r] = f2bf(acc[mt][nt][r] + bs);
                *(us4*)&oV[(size_t)ch*MROW + grow0] = o;
            }
        }
    }
}

// ---------------- proj GEMM split-K=2: partial bf16, no bias ---------------
__global__ __launch_bounds__(256) void gemm_proj_k(
    const unsigned short* __restrict__ A, const unsigned short* __restrict__ Bt,
    unsigned short* __restrict__ P)   // [2][MROW][1024]
{
    __shared__ unsigned short As[128*64];
    __shared__ unsigned short Bs[128*64];
    const int tid  = threadIdx.x;
    const int wv   = tid >> 6;
    const int lane = tid & 63;
    const int quad = lane >> 4;
    const int l16  = lane & 15;
    const int wm   = wv & 1, wn = wv >> 1;
    const int bm = blockIdx.y * 128, bn = blockIdx.x * 128;
    const int kz = blockIdx.z;

    GemmFrags F;
    gemm_setup(F, As, Bs, A, Bt, bm, bn, 1024);

    f32x4 acc[4][4];
    #pragma unroll
    for (int i = 0; i < 4; ++i)
        #pragma unroll
        for (int j = 0; j < 4; ++j) acc[i][j] = (f32x4){0.f,0.f,0.f,0.f};

    gemm_kloop<1>(F, acc, kz*512, kz*512 + 512);

    unsigned short* O = P + (size_t)kz*MROW*1024;
    #pragma unroll
    for (int mt = 0; mt < 4; ++mt) {
        const int m = bm + wm*64 + mt*16 + l16;
        #pragma unroll
        for (int nt = 0; nt < 4; ++nt) {
            const int n0 = bn + wn*64 + nt*16 + quad*4;
            us4 o;
            #pragma unroll
            for (int r = 0; r < 4; ++r) o[r] = f2bf(acc[mt][nt][r]);
            *(us4*)&O[(size_t)m*1024 + n0] = o;
        }
    }
}

// ---------------- flash attention v3 (lsum on VALU this round) -------------
__global__ __launch_bounds__(256, 2) void attn_k(
    const unsigned short* __restrict__ Qg,
    const unsigned short* __restrict__ Kg,
    const unsigned short* __restrict__ Vtg,
    unsigned short* __restrict__ CTX)
{
    __shared__ __align__(16) char lds_raw[51200];
    unsigned short* Qs = (unsigned short*)lds_raw;            // [128][72]
    unsigned short* Ks = (unsigned short*)(lds_raw + 18432);  // [2][64][64]
    unsigned short* Vs = (unsigned short*)(lds_raw + 34816);  // [2][64][64]
    float* Od = (float*)lds_raw;                              // [2][64][68]
    float* Ld = (float*)(lds_raw + 34816);                    // [2][64]

    const int tid  = threadIdx.x;
    const int wv   = tid >> 6;
    const int lane = tid & 63;
    const int quad = lane >> 4;
    const int l16  = lane & 15;
    const int wq   = wv & 1;
    const int wk   = wv >> 1;
    const int qb   = blockIdx.x * 128;
    const int h    = blockIdx.y;
    const int b    = blockIdx.z;

    {
        const int row = tid & 127, cb = (tid >> 7) * 32;
        const unsigned short* Qrow = Qg + ((size_t)(b*TSEQ + qb + row))*DMOD + h*HDIM + cb;
        #pragma unroll
        for (int j = 0; j < 4; ++j)
            *(us8*)&Qs[row*72 + cb + j*8] = *(const us8*)&Qrow[j*8];
    }
    __syncthreads();
    bf16x8 qf[4][2];
    #pragma unroll
    for (int nt = 0; nt < 4; ++nt)
        #pragma unroll
        for (int kh = 0; kh < 2; ++kh)
            qf[nt][kh] = *(const bf16x8*)&Qs[(wq*64 + nt*16 + l16)*72 + kh*32 + quad*8];

    const int sr = lane >> 3;
    const int sc = lane & 7;
    const bool isK = (wv < 2);
    const int half = wv & 1;
    const unsigned short* gbase;
    unsigned int goff[8];
    unsigned short* ldst;
    if (isK) {
        gbase = Kg + ((size_t)(b*TSEQ + half*1024))*DMOD + h*HDIM;
        #pragma unroll
        for (int s = 0; s < 8; ++s) {
            const int R = s*8 + sr;
            const int gc = sc ^ ((R ^ (R >> 2)) & 7);
            goff[s] = (unsigned)(R*DMOD + gc*8);
        }
        ldst = Ks + half*4096;
    } else {
        gbase = Vtg + ((size_t)(h*HDIM))*MROW + b*TSEQ + half*1024;
        #pragma unroll
        for (int s = 0; s < 8; ++s) {
            const int D = s*8 + sr;
            const int gc = sc ^ (D & 7);
            goff[s] = (unsigned)(D*MROW + gc*8);
        }
        ldst = Vs + half*4096;
    }
    const size_t gstep = isK ? (size_t)64*DMOD : (size_t)64;

    const int rowA_l = (l16 >> 2)*8 + (l16 & 3);
    const int rowB_l = rowA_l + 4;
    const int swA = (rowA_l ^ (rowA_l >> 2)) & 7;
    const int swB = (rowB_l ^ (rowB_l >> 2)) & 7;
    const unsigned short* KsW = Ks + wk*4096;
    const unsigned short* VsW = Vs + wk*4096;

    f32x4 oacc[4][4];
    float ls[4] = {0.f, 0.f, 0.f, 0.f};
    #pragma unroll
    for (int dt = 0; dt < 4; ++dt)
        #pragma unroll
        for (int nt = 0; nt < 4; ++nt) oacc[dt][nt] = (f32x4){0.f,0.f,0.f,0.f};

    for (int it = 0; it < 16; ++it) {
        __syncthreads();
        #pragma unroll
        for (int s = 0; s < 8; ++s)
            gld_lds16(gbase + (size_t)it*gstep + goff[s], ldst + s*512);
        __syncthreads();

        #pragma unroll
        for (int gl = 0; gl < 2; ++gl) {
            const int rA = gl*32 + rowA_l;
            const int rB = gl*32 + rowB_l;
            bf16x8 ka0 = *(const bf16x8*)&KsW[rA*64 + ((quad     ^ swA))*8];
            bf16x8 ka1 = *(const bf16x8*)&KsW[rA*64 + (((4+quad) ^ swA))*8];
            bf16x8 kb0 = *(const bf16x8*)&KsW[rB*64 + ((quad     ^ swB))*8];
            bf16x8 kb1 = *(const bf16x8*)&KsW[rB*64 + (((4+quad) ^ swB))*8];
            bf16x8 vf[4];
            #pragma unroll
            for (int dt = 0; dt < 4; ++dt)
                vf[dt] = *(const bf16x8*)&VsW[(dt*16 + l16)*64 + ((gl*4 + quad) ^ (l16 & 7))*8];

            #pragma unroll
            for (int nt = 0; nt < 4; ++nt) {
                f32x4 z = (f32x4){0.f,0.f,0.f,0.f};
                z = __builtin_amdgcn_mfma_f32_16x16x32_bf16(ka0, qf[nt][0], z, 0, 0, 0);
                f32x4 sA = __builtin_amdgcn_mfma_f32_16x16x32_bf16(ka1, qf[nt][1], z, 0, 0, 0);
                z = (f32x4){0.f,0.f,0.f,0.f};
                z = __builtin_amdgcn_mfma_f32_16x16x32_bf16(kb0, qf[nt][0], z, 0, 0, 0);
                f32x4 sB = __builtin_amdgcn_mfma_f32_16x16x32_bf16(kb1, qf[nt][1], z, 0, 0, 0);

                float eA[4], eB[4];
                #pragma unroll
                for (int r = 0; r < 4; ++r) { eA[r] = fexp2(sA[r]); eB[r] = fexp2(sB[r]); }
                // lsum on VALU (light pipe) — frees 8 MFMA slots/iter
                ls[nt] += ((eA[0]+eA[1]) + (eA[2]+eA[3])) + ((eB[0]+eB[1]) + (eB[2]+eB[3]));
                union { unsigned d[4]; bf16x8 v; } up;
                up.d[0] = __builtin_amdgcn_perm(__float_as_uint(eA[1]), __float_as_uint(eA[0]), 0x07060302);
                up.d[1] = __builtin_amdgcn_perm(__float_as_uint(eA[3]), __float_as_uint(eA[2]), 0x07060302);
                up.d[2] = __builtin_amdgcn_perm(__float_as_uint(eB[1]), __float_as_uint(eB[0]), 0x07060302);
                up.d[3] = __builtin_amdgcn_perm(__float_as_uint(eB[3]), __float_as_uint(eB[2]), 0x07060302);
                const bf16x8 pf = up.v;

                #pragma unroll
                for (int dt = 0; dt < 4; ++dt)
                    oacc[dt][nt] = __builtin_amdgcn_mfma_f32_16x16x32_bf16(vf[dt], pf, oacc[dt][nt], 0, 0, 0);
            }
        }
    }

    // lane's ls covers only its quad's 8 keys/step — reduce across quads
    #pragma unroll
    for (int nt = 0; nt < 4; ++nt) {
        ls[nt] += __shfl_xor(ls[nt], 16, 64);
        ls[nt] += __shfl_xor(ls[nt], 32, 64);
    }

    __syncthreads();
    if (wk == 0) {
        float* od = Od + wq*64*68;
        #pragma unroll
        for (int nt = 0; nt < 4; ++nt) {
            #pragma unroll
            for (int dt = 0; dt < 4; ++dt)
                *(f32x4*)&od[(nt*16 + l16)*68 + dt*16 + quad*4] = oacc[dt][nt];
            if (quad == 0) Ld[wq*64 + nt*16 + l16] = ls[nt];
        }
    }
    __syncthreads();
    if (wk == 1) {
        const float* od = Od + wq*64*68;
        #pragma unroll
        for (int nt = 0; nt < 4; ++nt) {
            const float l = Ld[wq*64 + nt*16 + l16] + ls[nt];
            const float inv = 1.f / l;
            const int q = qb + wq*64 + nt*16 + l16;
            unsigned short* crow = CTX + ((size_t)(b*TSEQ + q))*DMOD + h*HDIM;
            #pragma unroll
            for (int dt = 0; dt < 4; ++dt) {
                f32x4 p = *(const f32x4*)&od[(nt*16 + l16)*68 + dt*16 + quad*4];
                us4 o;
                #pragma unroll
                for (int r = 0; r < 4; ++r) o[r] = f2bf((p[r] + oacc[dt][nt][r]) * inv);
                *(us4*)&crow[dt*16 + quad*4] = o;
            }
        }
    }
}

// ---------- split-K reduce + bias + residual(bf16 x) + LayerNorm -----------
__global__ __launch_bounds__(256) void red_ln_k(
    const unsigned short* __restrict__ Xb, const unsigned short* __restrict__ P,
    const float* __restrict__ bo,
    const float* __restrict__ gamma, const float* __restrict__ beta,
    float* __restrict__ out)
{
    __shared__ float rs[4], rss[4];
    const int row = blockIdx.x;
    const int tid = threadIdx.x;
    const int c = tid * 4;
    const us4 xv = *(const us4*)&Xb[(size_t)row*DMOD + c];
    const us4 p0 = *(const us4*)&P[(size_t)row*DMOD + c];
    const us4 p1 = *(const us4*)&P[(size_t)(MROW + row)*DMOD + c];
    const float4 bv4 = *(const float4*)&bo[c];
    const float v0 = bf2f(xv[0]) + bf2f(p0[0]) + bf2f(p1[0]) + bv4.x;
    const float v1 = bf2f(xv[1]) + bf2f(p0[1]) + bf2f(p1[1]) + bv4.y;
    const float v2 = bf2f(xv[2]) + bf2f(p0[2]) + bf2f(p1[2]) + bv4.z;
    const float v3 = bf2f(xv[3]) + bf2f(p0[3]) + bf2f(p1[3]) + bv4.w;
    float s  = v0 + v1 + v2 + v3;
    float ss = v0*v0 + v1*v1 + v2*v2 + v3*v3;
    #pragma unroll
    for (int o = 32; o > 0; o >>= 1) {
        s  += __shfl_down(s,  o, 64);
        ss += __shfl_down(ss, o, 64);
    }
    if ((tid & 63) == 0) { rs[tid >> 6] = s; rss[tid >> 6] = ss; }
    __syncthreads();
    s  = rs[0] + rs[1] + rs[2] + rs[3];
    ss = rss[0] + rss[1] + rss[2] + rss[3];
    const float mean = s * (1.f/DMOD);
    const float var  = ss * (1.f/DMOD) - mean*mean;
    const float rstd = rsqrtf(var + LNEPS);
    const float4 gv = *(const float4*)&gamma[c];
    const float4 bv = *(const float4*)&beta[c];
    float4 o;
    o.x = (v0 - mean)*rstd*gv.x + bv.x;
    o.y = (v1 - mean)*rstd*gv.y + bv.y;
    o.z = (v2 - mean)*rstd*gv.z + bv.z;
    o.w = (v3 - mean)*rstd*gv.w + bv.w;
    *(float4*)&out[(size_t)row*DMOD + c] = o;
}

extern "C" void kernel_launch(void* const* d_in, const int* in_sizes, int n_in,
                              void* d_out, int out_size, void* d_ws, size_t ws_size,
                              hipStream_t stream) {
    const float* x     = (const float*)d_in[0];
    const float* wq    = (const float*)d_in[1];
    const float* bq    = (const float*)d_in[2];
    const float* wk    = (const float*)d_in[3];
    const float* bk    = (const float*)d_in[4];
    const float* wvp   = (const float*)d_in[5];
    const float* bvp   = (const float*)d_in[6];
    const float* wo    = (const float*)d_in[7];
    const float* bo    = (const float*)d_in[8];
    const float* gamma = (const float*)d_in[9];
    const float* beta  = (const float*)d_in[10];
    float* out = (float*)d_out;

    // ws layout (bf16 elems), 48 MB total
    unsigned short* Xb    = (unsigned short*)d_ws;          // [4096][1024]
    unsigned short* WqkvT = Xb    + (size_t)MROW*DMOD;      // [3072][1024]
    unsigned short* WoT   = WqkvT + (size_t)3072*1024;      // [1024][1024]
    unsigned short* Qb    = WoT   + (size_t)1024*1024;      // [4096][1024]
    unsigned short* Kb    = Qb    + (size_t)MROW*DMOD;      // [4096][1024]
    unsigned short* VtG   = Kb    + (size_t)MROW*DMOD;      // [1024][4096]
    unsigned short* CTXb  = VtG   + (size_t)DMOD*MROW;      // [4096][1024]
    unsigned short* Pp    = Qb;   // proj partials [2][4096][1024] overlay Qb+Kb

    prep_k<<<3072, 256, 0, stream>>>(x, wq, wk, wvp, wo, Xb, WqkvT, WoT);

    gemm_qkv_k<<<dim3(3072/128, MROW/128), 256, 0, stream>>>(
        Xb, WqkvT, bq, bk, bvp, Qb, Kb, VtG);

    attn_k<<<dim3(TSEQ/128, NHEAD, BSZ), 256, 0, stream>>>(Qb, Kb, VtG, CTXb);

    gemm_proj_k<<<dim3(DMOD/128, MROW/128, 2), 256, 0, stream>>>(CTXb, WoT, Pp);

    red_ln_k<<<MROW, 256, 0, stream>>>(Xb, Pp, bo, gamma, beta, out);
}